// Round 3
// baseline (301.988 us; speedup 1.0000x reference)
//
#include <hip/hip_runtime.h>
#include <hip/hip_bf16.h>
#include <stdint.h>

#define L_DIM 2048
#define B_DIM 8
#define D_DIM 1024
#define M_DIM (L_DIM * B_DIM)   // 16384 rows
#define N_DIM (3 * D_DIM)       // 3072
#define K_DIM D_DIM             // 1024
#define CH    (B_DIM * D_DIM)   // 8192 scan channels
#define EPSLN 1e-5f
#define NC 128                  // scan chunks (2048 blocks -> 8/CU)
#define CL (L_DIM / NC)         // 16 steps per chunk

// ---- GEMM geometry (256^2 tile, relaxed 1-barrier-per-K-tile schedule) ----
#define BM 256
#define BN 256
#define BK 64
#define NT (K_DIM / BK)         // 16 K-tiles
#define GX (N_DIM / BN)         // 12
#define GY (M_DIM / BM)         // 64
#define NWG (GX * GY)           // 768 (divisible by 8 -> bijective XCD swizzle)

typedef __attribute__((ext_vector_type(8))) short short8;
typedef __attribute__((ext_vector_type(4))) float floatx4;

static __device__ __forceinline__ float bf16_lo(unsigned int p) {
    union { unsigned int u; float f; } v; v.u = p << 16; return v.f;
}
static __device__ __forceinline__ float bf16_hi(unsigned int p) {
    union { unsigned int u; float f; } v; v.u = p & 0xffff0000u; return v.f;
}
static __device__ __forceinline__ unsigned short f32_to_bf16(float f) {
    union { float f; unsigned int u; } v;
    v.f = f;
    unsigned int u = v.u;
    u += 0x7fffu + ((u >> 16) & 1u);   // round-to-nearest-even
    return (unsigned short)(u >> 16);
}
static __device__ __forceinline__ float sigmoidf_fast(float v) {
    return 1.0f / (1.0f + __expf(-v));
}
static __device__ __forceinline__ float tanhf_fast(float c) {
    return 1.0f - 2.0f / (1.0f + __expf(2.0f * c));
}

// async global -> LDS, 16B per lane (global_load_lds_dwordx4)
static __device__ __forceinline__ void async16(const void* g, void* l) {
    __builtin_amdgcn_global_load_lds(
        (const __attribute__((address_space(1))) unsigned int*)g,
        (__attribute__((address_space(3))) unsigned int*)l,
        16, 0, 0);
}

// ---------------- LayerNorm: x[M,D] fp32 -> x_norm bf16 [M,D] + mean/rstd ----
__global__ __launch_bounds__(256) void ln_kernel(const float* __restrict__ x,
                                                 const float* __restrict__ gamma,
                                                 const float* __restrict__ beta,
                                                 unsigned short* __restrict__ xn,
                                                 float* __restrict__ meanOut,
                                                 float* __restrict__ rstdOut) {
    const int row = blockIdx.x;
    const int tid = threadIdx.x;
    const float4* xr = (const float4*)(x + (size_t)row * D_DIM);
    float4 v = xr[tid];
    float s  = v.x + v.y + v.z + v.w;
    float s2 = v.x * v.x + v.y * v.y + v.z * v.z + v.w * v.w;
    #pragma unroll
    for (int o = 32; o > 0; o >>= 1) {
        s  += __shfl_xor(s, o, 64);
        s2 += __shfl_xor(s2, o, 64);
    }
    __shared__ float red[8];
    const int wid = tid >> 6;
    if ((tid & 63) == 0) { red[wid] = s; red[4 + wid] = s2; }
    __syncthreads();
    s  = red[0] + red[1] + red[2] + red[3];
    s2 = red[4] + red[5] + red[6] + red[7];
    const float mean = s * (1.0f / D_DIM);
    const float var  = s2 * (1.0f / D_DIM) - mean * mean;
    const float rstd = rsqrtf(var + EPSLN);
    if (tid == 0) { meanOut[row] = mean; rstdOut[row] = rstd; }
    const int col = tid * 4;
    const float4 g = *(const float4*)(gamma + col);
    const float4 b = *(const float4*)(beta + col);
    unsigned short o0 = f32_to_bf16((v.x - mean) * rstd * g.x + b.x);
    unsigned short o1 = f32_to_bf16((v.y - mean) * rstd * g.y + b.y);
    unsigned short o2 = f32_to_bf16((v.z - mean) * rstd * g.z + b.z);
    unsigned short o3 = f32_to_bf16((v.w - mean) * rstd * g.w + b.w);
    uint2 packed;
    packed.x = (unsigned int)o0 | ((unsigned int)o1 << 16);
    packed.y = (unsigned int)o2 | ((unsigned int)o3 << 16);
    *(uint2*)(xn + (size_t)row * D_DIM + col) = packed;
}

// ---------------- W fp32 [3D, D] -> bf16 ----------------
__global__ __launch_bounds__(256) void wconv_kernel(const float* __restrict__ W,
                                                    unsigned short* __restrict__ Wb) {
    const size_t i = ((size_t)blockIdx.x * 256 + threadIdx.x) * 4;
    float4 v = *(const float4*)(W + i);
    uint2 packed;
    packed.x = (unsigned int)f32_to_bf16(v.x) | ((unsigned int)f32_to_bf16(v.y) << 16);
    packed.y = (unsigned int)f32_to_bf16(v.z) | ((unsigned int)f32_to_bf16(v.w) << 16);
    *(uint2*)(Wb + i) = packed;
}

// ---------------- GEMM: ufr[m,e] = sum_k xn[m,k] * W[e,k]  (NT, bf16 MFMA) ---
// 256x256 tile, BK=64, 8 waves (2Mx4N). ROUND-3 SYNC SKELETON:
// The lockstep phase structure (rounds 1-2) serialized the LDS pipe and the
// MFMA pipe (all waves do RD -> lgkm -> MFMA between barrier pairs), capping
// MfmaUtil at ~30%. This version removes the lockstep:
//   - ONE s_barrier + ONE vmcnt(0) per K-tile (at tile end).
//   - Staging for tile kt+1 issues as a single 8-load burst at the START of
//     tile kt -> at the end-of-tile drain the loads are ~2400 cy old (>> 900
//     cy worst-case HBM latency) -> the vmcnt(0) drain costs ~nothing.
//   - NO manual lgkm waits / sched pins inside the tile: ds_reads are plain
//     loads feeding MFMA intrinsics; the compiler's dependency-driven
//     lgkmcnt scheduling interleaves ds_read / stage-issue / MFMA freely,
//     and 2 waves/SIMD overlap LDS traffic with MFMA.
// Safety ledger:
//   - reads of buf(kt): staged during kt-1, all 8 loads of every wave retired
//     before the end-of-(kt-1) barrier (per-wave vmcnt(0) precedes it) ->
//     chip-visible after the barrier. Any read order inside kt is safe.
//   - staging into nbuf during kt: nbuf was last read during kt-1; those
//     ds_reads completed before their wave entered the end-of-(kt-1) barrier
//     (the final MFMA consuming them forces lgkm drain) -> no WAR race.
//   - sched_barrier(0) after each s_barrier: the barrier intrinsic is not a
//     compiler memory fence; this pins loads from crossing the barrier point
//     (a hoisted next-tile ds_read would race other waves' in-flight stages).
// XOR swizzle: store-side global k-chunk = (tid&7)^(row&7) at linear LDS
// slot tid&7; read slot = (quad+4s)^(l16&7). 2-way aliasing (free, m136).
__global__ __launch_bounds__(512, 2) void gemm_kernel(const unsigned short* __restrict__ A,
                                                      const unsigned short* __restrict__ W,
                                                      unsigned short* __restrict__ u,
                                                      unsigned short* __restrict__ f,
                                                      unsigned short* __restrict__ r) {
    __shared__ __align__(16) unsigned short ldsA[2][BM * BK];   // 2 x 32 KiB
    __shared__ __align__(16) unsigned short ldsB[2][BM * BK];   // 2 x 32 KiB

    const int tid  = threadIdx.x;          // 0..511
    const int wave = tid >> 6;             // 0..7
    const int lane = tid & 63;
    const int quad = lane >> 4;
    const int l16  = lane & 15;
    const int wr   = wave >> 2;            // 0..1
    const int wc   = wave & 3;             // 0..3

    // T1: bijective XCD swizzle (NWG=768, 768%8==0)
    const int orig = blockIdx.y * GX + blockIdx.x;
    const int swz  = (orig & 7) * (NWG / 8) + (orig >> 3);
    const int tx   = swz % GX;
    const int ty   = swz / GX;
    const int m0   = ty * BM;
    const int n0   = tx * BN;

    // staging: thread -> (row tid>>3 within 64-row block, chunk tid&7)
    const int rS = tid >> 3;                          // 0..63
    const int kS = ((tid & 7) ^ (rS & 7)) * 8;        // pre-swizzled global k-chunk
    const unsigned short* gA = A + (size_t)(m0 + rS) * K_DIM + kS;
    const unsigned short* gB = W + (size_t)(n0 + rS) * K_DIM + kS;

    // fragment-read constants
    const int px     = l16 & 7;
    const int p0_8   = (quad ^ px) * 8;
    const int p1_8   = ((quad + 4) ^ px) * 8;
    const int l16_64 = l16 * 64;
    const int wr4096 = wr * 4096;
    const int wc2048 = wc * 2048;

    floatx4 acc[2][2][4][2] = {};
    short8 a[4][2];        // current mh: 4 M-frags x 2 k-substeps
    short8 b[2][2][2];     // [nh][j][s]: both nh halves stay live across a tile

#define STAGE_A(B_, KT_, H_) do { \
    async16(gA + (size_t)((H_) * 128) * K_DIM + (size_t)(KT_) * 64, \
            &ldsA[B_][(H_) * 8192 + (size_t)tid * 8]); \
    async16(gA + (size_t)((H_) * 128 + 64) * K_DIM + (size_t)(KT_) * 64, \
            &ldsA[B_][(H_) * 8192 + 4096 + (size_t)tid * 8]); \
} while (0)

#define STAGE_B(B_, KT_, H_) do { \
    async16(gB + (size_t)((H_) * 128) * K_DIM + (size_t)(KT_) * 64, \
            &ldsB[B_][(H_) * 8192 + (size_t)tid * 8]); \
    async16(gB + (size_t)((H_) * 128 + 64) * K_DIM + (size_t)(KT_) * 64, \
            &ldsB[B_][(H_) * 8192 + 4096 + (size_t)tid * 8]); \
} while (0)

#define RD_A(MH_) do { \
    const unsigned short* pa_ = &ldsA[buf][(MH_) * 8192 + wr4096 + l16_64]; \
    _Pragma("unroll") \
    for (int i_ = 0; i_ < 4; i_++) { \
        a[i_][0] = *(const short8*)(pa_ + i_ * 1024 + p0_8); \
        a[i_][1] = *(const short8*)(pa_ + i_ * 1024 + p1_8); \
    } \
} while (0)

#define RD_B(NH_) do { \
    const unsigned short* pb_ = &ldsB[buf][(NH_) * 8192 + wc2048 + l16_64]; \
    _Pragma("unroll") \
    for (int j_ = 0; j_ < 2; j_++) { \
        b[NH_][j_][0] = *(const short8*)(pb_ + j_ * 1024 + p0_8); \
        b[NH_][j_][1] = *(const short8*)(pb_ + j_ * 1024 + p1_8); \
    } \
} while (0)

#define MFMA_Q(MH_, NH_) do { \
    __builtin_amdgcn_s_setprio(1); \
    _Pragma("unroll") \
    for (int i_ = 0; i_ < 4; i_++) { \
        _Pragma("unroll") \
        for (int j_ = 0; j_ < 2; j_++) { \
            acc[MH_][NH_][i_][j_] = __builtin_amdgcn_mfma_f32_16x16x32_bf16( \
                a[i_][0], b[NH_][j_][0], acc[MH_][NH_][i_][j_], 0, 0, 0); \
            acc[MH_][NH_][i_][j_] = __builtin_amdgcn_mfma_f32_16x16x32_bf16( \
                a[i_][1], b[NH_][j_][1], acc[MH_][NH_][i_][j_], 0, 0, 0); \
        } \
    } \
    __builtin_amdgcn_s_setprio(0); \
} while (0)

#define TILE_SYNC do { \
    asm volatile("s_waitcnt vmcnt(0)" ::: "memory"); \
    __builtin_amdgcn_s_barrier(); \
    __builtin_amdgcn_sched_barrier(0); \
} while (0)

    // prologue: stage tile 0 into buf 0, drain once
    STAGE_A(0, 0, 0); STAGE_B(0, 0, 0);
    STAGE_A(0, 0, 1); STAGE_B(0, 0, 1);
    TILE_SYNC;

    // main loop: tile kt from buf; burst-stage tile kt+1 into nbuf at tile
    // start; one drain+barrier at tile end. Compiler schedules the interior.
    for (int kt = 0; kt < NT - 1; ++kt) {
        const int buf  = kt & 1;
        const int nbuf = buf ^ 1;
        STAGE_A(nbuf, kt + 1, 0); STAGE_B(nbuf, kt + 1, 0);
        STAGE_A(nbuf, kt + 1, 1); STAGE_B(nbuf, kt + 1, 1);
        RD_A(0); RD_B(0);
        MFMA_Q(0, 0);
        RD_B(1);
        MFMA_Q(0, 1);
        RD_A(1);
        MFMA_Q(1, 1);
        MFMA_Q(1, 0);
        TILE_SYNC;
    }

    // tail tile NT-1: no staging, no trailing sync (epilogue uses regs only)
    {
        const int buf = (NT - 1) & 1;
        RD_A(0); RD_B(0);
        MFMA_Q(0, 0);
        RD_B(1);
        MFMA_Q(0, 1);
        RD_A(1);
        MFMA_Q(1, 1);
        MFMA_Q(1, 0);
    }

#undef TILE_SYNC
#undef MFMA_Q
#undef RD_A
#undef RD_B
#undef STAGE_A
#undef STAGE_B

    // Epilogue: region uniform per block (BN=256 divides the 1024 gate span)
    const int region = n0 >> 10;          // 0 -> u, 1 -> f, 2 -> r
    const int nnb = n0 & 1023;
    unsigned short* dst = (region == 0) ? u : ((region == 1) ? f : r);
    const bool sig = (region != 0);
    #pragma unroll
    for (int mh = 0; mh < 2; mh++) {
        #pragma unroll
        for (int nh = 0; nh < 2; nh++) {
            #pragma unroll
            for (int i = 0; i < 4; i++) {
                #pragma unroll
                for (int j = 0; j < 2; j++) {
                    #pragma unroll
                    for (int t = 0; t < 4; t++) {
                        const int gm = m0 + mh * 128 + wr * 64 + i * 16 + quad * 4 + t;
                        const int nn = nnb + nh * 128 + wc * 32 + j * 16 + l16;
                        float v = acc[mh][nh][i][j][t];
                        if (sig) v = sigmoidf_fast(v);
                        dst[(size_t)gm * D_DIM + nn] = f32_to_bf16(v);
                    }
                }
            }
        }
    }
}

// ---------------- Scan phase 1: per-chunk affine reduce (2 channels/thread) --
// c_out = A * c_in + b over CL steps;  A = prod f_t,  b = folded offsets
__global__ __launch_bounds__(256) void scan_reduce(const unsigned short* __restrict__ f,
                                                   const unsigned short* __restrict__ u,
                                                   float* __restrict__ Ac,
                                                   float* __restrict__ bc) {
    const int ch2   = (blockIdx.x * 256 + threadIdx.x) * 2;
    const int chunk = blockIdx.y;
    const size_t base = (size_t)chunk * CL * CH + ch2;
    float A0 = 1.0f, b0 = 0.0f, A1 = 1.0f, b1 = 0.0f;
    #pragma unroll
    for (int i = 0; i < CL; i++) {
        const size_t idx = base + (size_t)i * CH;
        const unsigned int fp = *(const unsigned int*)(f + idx);
        const unsigned int up = *(const unsigned int*)(u + idx);
        const float f0 = bf16_lo(fp), f1 = bf16_hi(fp);
        const float u0 = bf16_lo(up), u1 = bf16_hi(up);
        b0 = f0 * (b0 - u0) + u0;   // f*b + (1-f)*u
        b1 = f1 * (b1 - u1) + u1;
        A0 *= f0;
        A1 *= f1;
    }
    *(float2*)(Ac + chunk * CH + ch2) = make_float2(A0, A1);
    *(float2*)(bc + chunk * CH + ch2) = make_float2(b0, b1);
}

// ---------------- Scan phase 2: spine (exclusive scan over chunks) -----------
__global__ __launch_bounds__(256) void scan_spine(const float* __restrict__ Ac,
                                                  const float* __restrict__ bc,
                                                  const float* __restrict__ c0,
                                                  float* __restrict__ cst) {
    const int ch = blockIdx.x * 256 + threadIdx.x;
    float c = c0[ch];
    #pragma unroll 16
    for (int j = 0; j < NC; j++) {
        cst[j * CH + ch] = c;
        c = Ac[j * CH + ch] * c + bc[j * CH + ch];
    }
}

// ---------------- Scan phase 3: apply + fused output (2 channels/thread) -----
__global__ __launch_bounds__(256) void scan_apply(const unsigned short* __restrict__ f,
                                                  const unsigned short* __restrict__ u,
                                                  const unsigned short* __restrict__ r,
                                                  const float* __restrict__ x,
                                                  const float* __restrict__ meanIn,
                                                  const float* __restrict__ rstdIn,
                                                  const float* __restrict__ gamma,
                                                  const float* __restrict__ beta,
                                                  const float* __restrict__ cst,
                                                  float* __restrict__ out,
                                                  float* __restrict__ lastc) {
    const int ch2   = (blockIdx.x * 256 + threadIdx.x) * 2;
    const int chunk = blockIdx.y;
    const int bidx  = ch2 >> 10;       // batch index (uniform per block)
    const int d     = ch2 & 1023;
    const float2 g  = *(const float2*)(gamma + d);
    const float2 be = *(const float2*)(beta + d);
    const size_t base = (size_t)chunk * CL * CH + ch2;
    float2 cc = *(const float2*)(cst + chunk * CH + ch2);
    float c0v = cc.x, c1v = cc.y;
    #pragma unroll 4
    for (int i = 0; i < CL; i++) {
        const int rowLB = (chunk * CL + i) * B_DIM + bidx;   // uniform
        const float mu = meanIn[rowLB];
        const float rs = rstdIn[rowLB];
        const size_t idx = base + (size_t)i * CH;
        const unsigned int fp = *(const unsigned int*)(f + idx);
        const unsigned int up = *(const unsigned int*)(u + idx);
        const unsigned int rp = *(const unsigned int*)(r + idx);
        const float2 xv = *(const float2*)(x + idx);
        const float f0 = bf16_lo(fp), f1 = bf16_hi(fp);
        const float u0 = bf16_lo(up), u1 = bf16_hi(up);
        c0v = f0 * (c0v - u0) + u0;
        c1v = f1 * (c1v - u1) + u1;
        const float r0 = bf16_lo(rp), r1 = bf16_hi(rp);
        const float n0 = (xv.x - mu) * rs * g.x + be.x;
        const float n1 = (xv.y - mu) * rs * g.y + be.y;
        float2 o;
        o.x = xv.x + r0 * tanhf_fast(c0v) + (1.0f - r0) * n0;
        o.y = xv.y + r1 * tanhf_fast(c1v) + (1.0f - r1) * n1;
        *(float2*)(out + idx) = o;
    }
    if (chunk == NC - 1) *(float2*)(lastc + ch2) = make_float2(c0v, c1v);
}

extern "C" void kernel_launch(void* const* d_in, const int* in_sizes, int n_in,
                              void* d_out, int out_size, void* d_ws, size_t ws_size,
                              hipStream_t stream) {
    const float* x     = (const float*)d_in[0];   // (L,B,D)
    const float* c0    = (const float*)d_in[1];   // (B,D)
    const float* W     = (const float*)d_in[2];   // (3D,D)
    const float* gamma = (const float*)d_in[3];   // (D,)
    const float* beta  = (const float*)d_in[4];   // (D,)

    float* out   = (float*)d_out;                       // (L,B,D)
    float* lastc = out + (size_t)M_DIM * D_DIM;         // (B,D)

    char* ws = (char*)d_ws;
    unsigned short* xn = (unsigned short*)ws;  ws += (size_t)M_DIM * K_DIM * 2;  // 33.5 MB
    unsigned short* Wb = (unsigned short*)ws;  ws += (size_t)N_DIM * K_DIM * 2;  // 6.3 MB
    unsigned short* u  = (unsigned short*)ws;  ws += (size_t)M_DIM * D_DIM * 2;  // 33.5 MB
    unsigned short* f  = (unsigned short*)ws;  ws += (size_t)M_DIM * D_DIM * 2;  // 33.5 MB
    unsigned short* r  = (unsigned short*)ws;  ws += (size_t)M_DIM * D_DIM * 2;  // 33.5 MB
    float* meanBuf = (float*)ws;               ws += (size_t)M_DIM * 4;
    float* rstdBuf = (float*)ws;               ws += (size_t)M_DIM * 4;
    float* Ac  = (float*)ws;                   ws += (size_t)NC * CH * 4;
    float* bc  = (float*)ws;                   ws += (size_t)NC * CH * 4;
    float* cst = (float*)ws;                   ws += (size_t)NC * CH * 4;

    ln_kernel<<<M_DIM, 256, 0, stream>>>(x, gamma, beta, xn, meanBuf, rstdBuf);
    wconv_kernel<<<(N_DIM * K_DIM) / 1024, 256, 0, stream>>>(W, Wb);
    gemm_kernel<<<dim3(GX, GY), 512, 0, stream>>>(xn, Wb, u, f, r);
    scan_reduce<<<dim3(CH / 512, NC), 256, 0, stream>>>(f, u, Ac, bc);
    scan_spine<<<CH / 256, 256, 0, stream>>>(Ac, bc, c0, cst);
    scan_apply<<<dim3(CH / 512, NC), 256, 0, stream>>>(f, u, r, x, meanBuf, rstdBuf,
                                                       gamma, beta, cst, out, lastc);
}

// Round 4
// 288.598 us; speedup vs baseline: 1.0464x; 1.0464x over previous
//
#include <hip/hip_runtime.h>
#include <hip/hip_bf16.h>
#include <stdint.h>

#define L_DIM 2048
#define B_DIM 8
#define D_DIM 1024
#define M_DIM (L_DIM * B_DIM)   // 16384 rows
#define N_DIM (3 * D_DIM)       // 3072
#define K_DIM D_DIM             // 1024
#define CH    (B_DIM * D_DIM)   // 8192 scan channels
#define EPSLN 1e-5f
#define NC 128                  // scan chunks (2048 blocks -> 8/CU)
#define CL (L_DIM / NC)         // 16 steps per chunk

// ---- GEMM geometry (256^2 tile, operand-resident octet schedule) ----
#define BM 256
#define BN 256
#define BK 64
#define NT (K_DIM / BK)         // 16 K-tiles
#define GX (N_DIM / BN)         // 12
#define GY (M_DIM / BM)         // 64
#define NWG (GX * GY)           // 768 (divisible by 8 -> bijective XCD swizzle)

typedef __attribute__((ext_vector_type(8))) short short8;
typedef __attribute__((ext_vector_type(4))) float floatx4;

static __device__ __forceinline__ float bf16_lo(unsigned int p) {
    union { unsigned int u; float f; } v; v.u = p << 16; return v.f;
}
static __device__ __forceinline__ float bf16_hi(unsigned int p) {
    union { unsigned int u; float f; } v; v.u = p & 0xffff0000u; return v.f;
}
static __device__ __forceinline__ unsigned short f32_to_bf16(float f) {
    union { float f; unsigned int u; } v;
    v.f = f;
    unsigned int u = v.u;
    u += 0x7fffu + ((u >> 16) & 1u);   // round-to-nearest-even
    return (unsigned short)(u >> 16);
}
static __device__ __forceinline__ float sigmoidf_fast(float v) {
    return 1.0f / (1.0f + __expf(-v));
}
static __device__ __forceinline__ float tanhf_fast(float c) {
    return 1.0f - 2.0f / (1.0f + __expf(2.0f * c));
}

// async global -> LDS, 16B per lane (global_load_lds_dwordx4)
static __device__ __forceinline__ void async16(const void* g, void* l) {
    __builtin_amdgcn_global_load_lds(
        (const __attribute__((address_space(1))) unsigned int*)g,
        (__attribute__((address_space(3))) unsigned int*)l,
        16, 0, 0);
}

// ---------------- LayerNorm: x[M,D] fp32 -> x_norm bf16 [M,D] + mean/rstd ----
__global__ __launch_bounds__(256) void ln_kernel(const float* __restrict__ x,
                                                 const float* __restrict__ gamma,
                                                 const float* __restrict__ beta,
                                                 unsigned short* __restrict__ xn,
                                                 float* __restrict__ meanOut,
                                                 float* __restrict__ rstdOut) {
    const int row = blockIdx.x;
    const int tid = threadIdx.x;
    const float4* xr = (const float4*)(x + (size_t)row * D_DIM);
    float4 v = xr[tid];
    float s  = v.x + v.y + v.z + v.w;
    float s2 = v.x * v.x + v.y * v.y + v.z * v.z + v.w * v.w;
    #pragma unroll
    for (int o = 32; o > 0; o >>= 1) {
        s  += __shfl_xor(s, o, 64);
        s2 += __shfl_xor(s2, o, 64);
    }
    __shared__ float red[8];
    const int wid = tid >> 6;
    if ((tid & 63) == 0) { red[wid] = s; red[4 + wid] = s2; }
    __syncthreads();
    s  = red[0] + red[1] + red[2] + red[3];
    s2 = red[4] + red[5] + red[6] + red[7];
    const float mean = s * (1.0f / D_DIM);
    const float var  = s2 * (1.0f / D_DIM) - mean * mean;
    const float rstd = rsqrtf(var + EPSLN);
    if (tid == 0) { meanOut[row] = mean; rstdOut[row] = rstd; }
    const int col = tid * 4;
    const float4 g = *(const float4*)(gamma + col);
    const float4 b = *(const float4*)(beta + col);
    unsigned short o0 = f32_to_bf16((v.x - mean) * rstd * g.x + b.x);
    unsigned short o1 = f32_to_bf16((v.y - mean) * rstd * g.y + b.y);
    unsigned short o2 = f32_to_bf16((v.z - mean) * rstd * g.z + b.z);
    unsigned short o3 = f32_to_bf16((v.w - mean) * rstd * g.w + b.w);
    uint2 packed;
    packed.x = (unsigned int)o0 | ((unsigned int)o1 << 16);
    packed.y = (unsigned int)o2 | ((unsigned int)o3 << 16);
    *(uint2*)(xn + (size_t)row * D_DIM + col) = packed;
}

// ---------------- W fp32 [3D, D] -> bf16 ----------------
__global__ __launch_bounds__(256) void wconv_kernel(const float* __restrict__ W,
                                                    unsigned short* __restrict__ Wb) {
    const size_t i = ((size_t)blockIdx.x * 256 + threadIdx.x) * 4;
    float4 v = *(const float4*)(W + i);
    uint2 packed;
    packed.x = (unsigned int)f32_to_bf16(v.x) | ((unsigned int)f32_to_bf16(v.y) << 16);
    packed.y = (unsigned int)f32_to_bf16(v.z) | ((unsigned int)f32_to_bf16(v.w) << 16);
    *(uint2*)(Wb + i) = packed;
}

// ---------------- GEMM: ufr[m,e] = sum_k xn[m,k] * W[e,k]  (NT, bf16 MFMA) ---
// 256x256 tile, BK=64, 8 waves (2Mx4N). ROUND-4: OPERAND-RESIDENT OCTETS.
// Diagnosis: r1/r2/r3 (3 different sync skeletons) all ~6900 cy/K-tile at
// MfmaUtil ~30% -> limiter is the read->consume-immediately dataflow: each
// MFMA block waits on LDS reads issued right before it, anti-correlating the
// LDS pipe and matrix pipe. Fix: every 8-MFMA octet consumes ONLY
// register-resident operands; each 4x ds_read quad is issued >=1 octet before
// first use (hidden under MFMAs whose operands are already resident).
// Register roles (all static indices, 64 VGPR of frags total):
//   aP: A0a -> A1a -> A0a'(next tile, prefetch)     [2 frags x 2 substeps]
//   aQ: A0b -> A1b                                   [2 x 2]
//   b0: B0  -> B0'(next tile, prefetch)              [2 x 2]
//   b1: B1 (re-read each tile)                       [2 x 2]
// Octet order: (0,0,a)(0,1,a)(0,0,b)(0,1,b) | BAR | (1,0,a)(1,1,a)(1,0,b)(1,1,b)
// Sync: ONE vmcnt(0)+s_barrier+sched_barrier(0) per K-tile, mid-tile (stage
// loads ~700-1300cy old there; 4 octets remain to hide nb-prefetch reads).
// Ledger: buf-reads retire before their consuming MFMA -> before the wave's
// barrier -> next tile's staging into buf (post-barrier) can't race them.
// nb-prefetch reads occur only after the vmcnt(0)+barrier proving nb staged
// chip-wide; sched_barrier(0) pins hoisting. Reg WAR = compiler dependency.
// XOR swizzle unchanged (store chunk (tid&7)^(row&7), read pos (quad+4s)^
// (l16&7); 2-way aliasing, free).
__global__ __launch_bounds__(512, 2) void gemm_kernel(const unsigned short* __restrict__ A,
                                                      const unsigned short* __restrict__ W,
                                                      unsigned short* __restrict__ u,
                                                      unsigned short* __restrict__ f,
                                                      unsigned short* __restrict__ r) {
    __shared__ __align__(16) unsigned short ldsA[2 * BM * BK];   // 2 x 32 KiB
    __shared__ __align__(16) unsigned short ldsB[2 * BM * BK];   // 2 x 32 KiB

    const int tid  = threadIdx.x;          // 0..511
    const int wave = tid >> 6;             // 0..7
    const int lane = tid & 63;
    const int quad = lane >> 4;
    const int l16  = lane & 15;
    const int wr   = wave >> 2;            // 0..1
    const int wc   = wave & 3;             // 0..3

    // T1: bijective XCD swizzle (NWG=768, 768%8==0)
    const int orig = blockIdx.y * GX + blockIdx.x;
    const int swz  = (orig & 7) * (NWG / 8) + (orig >> 3);
    const int tx   = swz % GX;
    const int ty   = swz / GX;
    const int m0   = ty * BM;
    const int n0   = tx * BN;

    // staging: thread -> (row tid>>3 within 64-row block, chunk tid&7)
    const int rS = tid >> 3;                          // 0..63
    const int kS = ((tid & 7) ^ (rS & 7)) * 8;        // pre-swizzled global k-chunk
    const unsigned short* gA = A + (size_t)(m0 + rS) * K_DIM + kS;
    const unsigned short* gB = W + (size_t)(n0 + rS) * K_DIM + kS;

    // fragment-read constants
    const int px     = l16 & 7;
    const int p0_8   = (quad ^ px) * 8;
    const int p1_8   = ((quad + 4) ^ px) * 8;
    const int l16_64 = l16 * 64;
    const int wr4096 = wr * 4096;
    const int wc2048 = wc * 2048;

    floatx4 acc[2][2][4][2] = {};
    short8 aP[2][2], aQ[2][2], b0[2][2], b1[2][2];   // 16 b128 = 64 VGPR

#define STAGE_A(BO_, KT_, H_) do { \
    async16(gA + (size_t)((H_) * 128) * K_DIM + (size_t)(KT_) * 64, \
            &ldsA[(BO_) + (H_) * 8192 + (size_t)tid * 8]); \
    async16(gA + (size_t)((H_) * 128 + 64) * K_DIM + (size_t)(KT_) * 64, \
            &ldsA[(BO_) + (H_) * 8192 + 4096 + (size_t)tid * 8]); \
} while (0)

#define STAGE_B(BO_, KT_, H_) do { \
    async16(gB + (size_t)((H_) * 128) * K_DIM + (size_t)(KT_) * 64, \
            &ldsB[(BO_) + (H_) * 8192 + (size_t)tid * 8]); \
    async16(gB + (size_t)((H_) * 128 + 64) * K_DIM + (size_t)(KT_) * 64, \
            &ldsB[(BO_) + (H_) * 8192 + 4096 + (size_t)tid * 8]); \
} while (0)

// read one A-quarter (2 M-frags x 2 substeps = 4 ds_read_b128)
#define RD_A4(ARR_, BO_, MH_, IH_) do { \
    const unsigned short* pa_ = &ldsA[(BO_) + (MH_) * 8192 + wr4096 + (IH_) * 2048 + l16_64]; \
    ARR_[0][0] = *(const short8*)(pa_ + p0_8); \
    ARR_[0][1] = *(const short8*)(pa_ + p1_8); \
    ARR_[1][0] = *(const short8*)(pa_ + 1024 + p0_8); \
    ARR_[1][1] = *(const short8*)(pa_ + 1024 + p1_8); \
} while (0)

// read one B-half (2 N-frags x 2 substeps = 4 ds_read_b128)
#define RD_B4(ARR_, BO_, NH_) do { \
    const unsigned short* pb_ = &ldsB[(BO_) + (NH_) * 8192 + wc2048 + l16_64]; \
    ARR_[0][0] = *(const short8*)(pb_ + p0_8); \
    ARR_[0][1] = *(const short8*)(pb_ + p1_8); \
    ARR_[1][0] = *(const short8*)(pb_ + 1024 + p0_8); \
    ARR_[1][1] = *(const short8*)(pb_ + 1024 + p1_8); \
} while (0)

// 8 MFMA on fully-resident operands: A-quarter ARR_ x B-half BRR_
#define OCT(ARR_, BRR_, MH_, NH_, IH_) do { \
    __builtin_amdgcn_s_setprio(1); \
    _Pragma("unroll") \
    for (int il_ = 0; il_ < 2; il_++) { \
        _Pragma("unroll") \
        for (int j_ = 0; j_ < 2; j_++) { \
            acc[MH_][NH_][(IH_)*2 + il_][j_] = __builtin_amdgcn_mfma_f32_16x16x32_bf16( \
                ARR_[il_][0], BRR_[j_][0], acc[MH_][NH_][(IH_)*2 + il_][j_], 0, 0, 0); \
            acc[MH_][NH_][(IH_)*2 + il_][j_] = __builtin_amdgcn_mfma_f32_16x16x32_bf16( \
                ARR_[il_][1], BRR_[j_][1], acc[MH_][NH_][(IH_)*2 + il_][j_], 0, 0, 0); \
        } \
    } \
    __builtin_amdgcn_s_setprio(0); \
} while (0)

#define TILE_BARRIER do { \
    asm volatile("s_waitcnt vmcnt(0)" ::: "memory"); \
    __builtin_amdgcn_s_barrier(); \
    __builtin_amdgcn_sched_barrier(0); \
} while (0)

    // prologue: stage tile 0 into buf 0; sync; pre-load A0a and B0
    STAGE_A(0, 0, 0); STAGE_B(0, 0, 0);
    STAGE_A(0, 0, 1); STAGE_B(0, 0, 1);
    TILE_BARRIER;
    RD_A4(aP, 0, 0, 0);      // A0a
    RD_B4(b0, 0, 0);         // B0

    // main loop: tiles 0..14; tile kt computes from bufS, stages kt+1 into nbS
    for (int kt = 0; kt < NT - 1; ++kt) {
        const int bufS = (kt & 1) << 14;          // *16384 shorts
        const int nbS  = bufS ^ 16384;
        // issue next-tile staging first (max age at mid-tile vmcnt(0))
        STAGE_A(nbS, kt + 1, 0); STAGE_B(nbS, kt + 1, 0);
        STAGE_A(nbS, kt + 1, 1); STAGE_B(nbS, kt + 1, 1);
        RD_B4(b1, bufS, 1);        // B1   -> used O2
        OCT(aP, b0, 0, 0, 0);      // O1: A0a*B0
        RD_A4(aQ, bufS, 0, 1);     // A0b  -> used O3
        OCT(aP, b1, 0, 1, 0);      // O2: A0a*B1   (aP dead)
        RD_A4(aP, bufS, 1, 0);     // A1a  -> used O5
        OCT(aQ, b0, 0, 0, 1);      // O3: A0b*B0
        OCT(aQ, b1, 0, 1, 1);      // O4: A0b*B1   (aQ dead)
        RD_A4(aQ, bufS, 1, 1);     // A1b  -> used O7
        TILE_BARRIER;              // nb staged chip-wide; buf reads all done
        OCT(aP, b0, 1, 0, 0);      // O5: A1a*B0
        OCT(aP, b1, 1, 1, 0);      // O6: A1a*B1   (aP dead)
        RD_A4(aP, nbS, 0, 0);      // A0a' (next tile) -> used next O1
        OCT(aQ, b0, 1, 0, 1);      // O7: A1b*B0   (b0 dead)
        RD_B4(b0, nbS, 0);         // B0'  (next tile) -> used next O1
        OCT(aQ, b1, 1, 1, 1);      // O8: A1b*B1
    }

    // tail tile 15 (buf 1): staged+synced by tile 14; no staging/prefetch
    {
        const int bufS = 16384;
        RD_B4(b1, bufS, 1);
        OCT(aP, b0, 0, 0, 0);
        RD_A4(aQ, bufS, 0, 1);
        OCT(aP, b1, 0, 1, 0);
        RD_A4(aP, bufS, 1, 0);
        OCT(aQ, b0, 0, 0, 1);
        OCT(aQ, b1, 0, 1, 1);
        RD_A4(aQ, bufS, 1, 1);
        OCT(aP, b0, 1, 0, 0);
        OCT(aP, b1, 1, 1, 0);
        OCT(aQ, b0, 1, 0, 1);
        OCT(aQ, b1, 1, 1, 1);
    }

#undef TILE_BARRIER
#undef OCT
#undef RD_B4
#undef RD_A4
#undef STAGE_B
#undef STAGE_A

    // Epilogue: region uniform per block (BN=256 divides the 1024 gate span)
    const int region = n0 >> 10;          // 0 -> u, 1 -> f, 2 -> r
    const int nnb = n0 & 1023;
    unsigned short* dst = (region == 0) ? u : ((region == 1) ? f : r);
    const bool sig = (region != 0);
    #pragma unroll
    for (int mh = 0; mh < 2; mh++) {
        #pragma unroll
        for (int nh = 0; nh < 2; nh++) {
            #pragma unroll
            for (int i = 0; i < 4; i++) {
                #pragma unroll
                for (int j = 0; j < 2; j++) {
                    #pragma unroll
                    for (int t = 0; t < 4; t++) {
                        const int gm = m0 + mh * 128 + wr * 64 + i * 16 + quad * 4 + t;
                        const int nn = nnb + nh * 128 + wc * 32 + j * 16 + l16;
                        float v = acc[mh][nh][i][j][t];
                        if (sig) v = sigmoidf_fast(v);
                        dst[(size_t)gm * D_DIM + nn] = f32_to_bf16(v);
                    }
                }
            }
        }
    }
}

// ---------------- Scan phase 1: per-chunk affine reduce (2 channels/thread) --
// c_out = A * c_in + b over CL steps;  A = prod f_t,  b = folded offsets
__global__ __launch_bounds__(256) void scan_reduce(const unsigned short* __restrict__ f,
                                                   const unsigned short* __restrict__ u,
                                                   float* __restrict__ Ac,
                                                   float* __restrict__ bc) {
    const int ch2   = (blockIdx.x * 256 + threadIdx.x) * 2;
    const int chunk = blockIdx.y;
    const size_t base = (size_t)chunk * CL * CH + ch2;
    float A0 = 1.0f, b0 = 0.0f, A1 = 1.0f, b1 = 0.0f;
    #pragma unroll
    for (int i = 0; i < CL; i++) {
        const size_t idx = base + (size_t)i * CH;
        const unsigned int fp = *(const unsigned int*)(f + idx);
        const unsigned int up = *(const unsigned int*)(u + idx);
        const float f0 = bf16_lo(fp), f1 = bf16_hi(fp);
        const float u0 = bf16_lo(up), u1 = bf16_hi(up);
        b0 = f0 * (b0 - u0) + u0;   // f*b + (1-f)*u
        b1 = f1 * (b1 - u1) + u1;
        A0 *= f0;
        A1 *= f1;
    }
    *(float2*)(Ac + chunk * CH + ch2) = make_float2(A0, A1);
    *(float2*)(bc + chunk * CH + ch2) = make_float2(b0, b1);
}

// ---------------- Scan phase 2: spine (exclusive scan over chunks) -----------
__global__ __launch_bounds__(256) void scan_spine(const float* __restrict__ Ac,
                                                  const float* __restrict__ bc,
                                                  const float* __restrict__ c0,
                                                  float* __restrict__ cst) {
    const int ch = blockIdx.x * 256 + threadIdx.x;
    float c = c0[ch];
    #pragma unroll 16
    for (int j = 0; j < NC; j++) {
        cst[j * CH + ch] = c;
        c = Ac[j * CH + ch] * c + bc[j * CH + ch];
    }
}

// ---------------- Scan phase 3: apply + fused output (2 channels/thread) -----
__global__ __launch_bounds__(256) void scan_apply(const unsigned short* __restrict__ f,
                                                  const unsigned short* __restrict__ u,
                                                  const unsigned short* __restrict__ r,
                                                  const float* __restrict__ x,
                                                  const float* __restrict__ meanIn,
                                                  const float* __restrict__ rstdIn,
                                                  const float* __restrict__ gamma,
                                                  const float* __restrict__ beta,
                                                  const float* __restrict__ cst,
                                                  float* __restrict__ out,
                                                  float* __restrict__ lastc) {
    const int ch2   = (blockIdx.x * 256 + threadIdx.x) * 2;
    const int chunk = blockIdx.y;
    const int bidx  = ch2 >> 10;       // batch index (uniform per block)
    const int d     = ch2 & 1023;
    const float2 g  = *(const float2*)(gamma + d);
    const float2 be = *(const float2*)(beta + d);
    const size_t base = (size_t)chunk * CL * CH + ch2;
    float2 cc = *(const float2*)(cst + chunk * CH + ch2);
    float c0v = cc.x, c1v = cc.y;
    #pragma unroll 4
    for (int i = 0; i < CL; i++) {
        const int rowLB = (chunk * CL + i) * B_DIM + bidx;   // uniform
        const float mu = meanIn[rowLB];
        const float rs = rstdIn[rowLB];
        const size_t idx = base + (size_t)i * CH;
        const unsigned int fp = *(const unsigned int*)(f + idx);
        const unsigned int up = *(const unsigned int*)(u + idx);
        const unsigned int rp = *(const unsigned int*)(r + idx);
        const float2 xv = *(const float2*)(x + idx);
        const float f0 = bf16_lo(fp), f1 = bf16_hi(fp);
        const float u0 = bf16_lo(up), u1 = bf16_hi(up);
        c0v = f0 * (c0v - u0) + u0;
        c1v = f1 * (c1v - u1) + u1;
        const float r0 = bf16_lo(rp), r1 = bf16_hi(rp);
        const float n0 = (xv.x - mu) * rs * g.x + be.x;
        const float n1 = (xv.y - mu) * rs * g.y + be.y;
        float2 o;
        o.x = xv.x + r0 * tanhf_fast(c0v) + (1.0f - r0) * n0;
        o.y = xv.y + r1 * tanhf_fast(c1v) + (1.0f - r1) * n1;
        *(float2*)(out + idx) = o;
    }
    if (chunk == NC - 1) *(float2*)(lastc + ch2) = make_float2(c0v, c1v);
}

extern "C" void kernel_launch(void* const* d_in, const int* in_sizes, int n_in,
                              void* d_out, int out_size, void* d_ws, size_t ws_size,
                              hipStream_t stream) {
    const float* x     = (const float*)d_in[0];   // (L,B,D)
    const float* c0    = (const float*)d_in[1];   // (B,D)
    const float* W     = (const float*)d_in[2];   // (3D,D)
    const float* gamma = (const float*)d_in[3];   // (D,)
    const float* beta  = (const float*)d_in[4];   // (D,)

    float* out   = (float*)d_out;                       // (L,B,D)
    float* lastc = out + (size_t)M_DIM * D_DIM;         // (B,D)

    char* ws = (char*)d_ws;
    unsigned short* xn = (unsigned short*)ws;  ws += (size_t)M_DIM * K_DIM * 2;  // 33.5 MB
    unsigned short* Wb = (unsigned short*)ws;  ws += (size_t)N_DIM * K_DIM * 2;  // 6.3 MB
    unsigned short* u  = (unsigned short*)ws;  ws += (size_t)M_DIM * D_DIM * 2;  // 33.5 MB
    unsigned short* f  = (unsigned short*)ws;  ws += (size_t)M_DIM * D_DIM * 2;  // 33.5 MB
    unsigned short* r  = (unsigned short*)ws;  ws += (size_t)M_DIM * D_DIM * 2;  // 33.5 MB
    float* meanBuf = (float*)ws;               ws += (size_t)M_DIM * 4;
    float* rstdBuf = (float*)ws;               ws += (size_t)M_DIM * 4;
    float* Ac  = (float*)ws;                   ws += (size_t)NC * CH * 4;
    float* bc  = (float*)ws;                   ws += (size_t)NC * CH * 4;
    float* cst = (float*)ws;                   ws += (size_t)NC * CH * 4;

    ln_kernel<<<M_DIM, 256, 0, stream>>>(x, gamma, beta, xn, meanBuf, rstdBuf);
    wconv_kernel<<<(N_DIM * K_DIM) / 1024, 256, 0, stream>>>(W, Wb);
    gemm_kernel<<<dim3(GX, GY), 512, 0, stream>>>(xn, Wb, u, f, r);
    scan_reduce<<<dim3(CH / 512, NC), 256, 0, stream>>>(f, u, Ac, bc);
    scan_spine<<<CH / 256, 256, 0, stream>>>(Ac, bc, c0, cst);
    scan_apply<<<dim3(CH / 512, NC), 256, 0, stream>>>(f, u, r, x, meanBuf, rstdBuf,
                                                       gamma, beta, cst, out, lastc);
}